// Round 16
// baseline (359.352 us; speedup 1.0000x reference)
//
#include <hip/hip_runtime.h>
#include <math.h>

#define NN     4096
#define NE     32768
#define NCAND  64
#define IND    128
#define HDM    256
#define NL     2
#define MAXD   64
#define GNPB   16   // GRU nodes per block
#define NS     4    // attention KV splits

typedef __attribute__((ext_vector_type(8))) short short8;
typedef __attribute__((ext_vector_type(4))) short short4b;
typedef __attribute__((ext_vector_type(4))) float f32x4;

__device__ __forceinline__ float sigf(float x) { return 1.0f / (1.0f + __expf(-x)); }
__device__ __forceinline__ float tanh_fast(float x) {
  float e = __expf(-2.0f * fabsf(x));
  float r = (1.0f - e) / (1.0f + e);
  return x < 0.0f ? -r : r;
}
__device__ __forceinline__ unsigned short f2bf(float f) {
  unsigned int x = __float_as_uint(f);
  x += 0x7fffu + ((x >> 16) & 1u);   // RNE
  return (unsigned short)(x >> 16);
}
__device__ __forceinline__ float bf2f(unsigned short u) {
  return __uint_as_float(((unsigned int)u) << 16);
}

// ================= weight/feature fp32->bf16 conversion + buffer zeroing =================
#define CVT_TOT 2523136
__global__ __launch_bounds__(256) void cvt_weights(
    const float* __restrict__ nf, const float* __restrict__ wih,
    const float* __restrict__ ain, const float* __restrict__ aout,
    const float* __restrict__ f1, const float* __restrict__ f2,
    const float* __restrict__ s1, const float* __restrict__ s2,
    const float* __restrict__ whh, unsigned short* __restrict__ dst,
    int* __restrict__ cnt, int* __restrict__ meta) {
  if (blockIdx.x < 16) cnt[blockIdx.x * 256 + threadIdx.x] = 0;
  else if (blockIdx.x == 16) meta[threadIdx.x] = 0;
  const size_t e = ((size_t)blockIdx.x * 256 + threadIdx.x) * 4;
  if (e >= CVT_TOT) return;
  const float* src;
  if (e < 524288)       src = nf   + e;
  else if (e < 622592)  src = wih  + (e - 524288);
  else if (e < 1015808) src = ain  + (e - 622592);
  else if (e < 1146880) src = aout + (e - 1015808);
  else if (e < 1671168) src = f1   + (e - 1146880);
  else if (e < 2195456) src = f2   + (e - 1671168);
  else if (e < 2260992) src = s1   + (e - 2195456);
  else if (e < 2326528) src = s2   + (e - 2260992);
  else                  src = whh  + (e - 2326528);
  const float4 v = *(const float4*)src;
  dst[e + 0] = f2bf(v.x); dst[e + 1] = f2bf(v.y);
  dst[e + 2] = f2bf(v.z); dst[e + 3] = f2bf(v.w);
}

// ================= GRU preprocessing =================
__global__ __launch_bounds__(256) void build_pos(const int* __restrict__ edges,
                                                 int* __restrict__ cnt, int* __restrict__ lists) {
  const int e = blockIdx.x * 256 + threadIdx.x;
  const int d = edges[2 * e + 1];
  const int slot = atomicAdd(&cnt[d], 1);
  if (slot < MAXD) lists[(size_t)d * MAXD + slot] = e;
}

__global__ __launch_bounds__(256) void sort_srcs(const int* __restrict__ edges,
                                                 int* __restrict__ cnt,
                                                 const int* __restrict__ lists,
                                                 int* __restrict__ srcs,
                                                 int* __restrict__ hist) {
  __shared__ int Ls[256][65];
  const int t = threadIdx.x;
  const int d = blockIdx.x * 256 + t;
  int c = cnt[d]; if (c > MAXD) c = MAXD;
  for (int i = 0; i < c; ++i) Ls[t][i] = lists[(size_t)d * MAXD + i];
  for (int i = 1; i < c; ++i) {
    const int key = Ls[t][i];
    int j = i - 1;
    while (j >= 0 && Ls[t][j] > key) { Ls[t][j + 1] = Ls[t][j]; --j; }
    Ls[t][j + 1] = key;
  }
  for (int i = 0; i < c; ++i) srcs[(size_t)d * MAXD + i] = edges[2 * Ls[t][i]];
  cnt[d] = c;
  atomicAdd(&hist[c], 1);
}

__global__ __launch_bounds__(256) void scan_prep(const int* __restrict__ hist,
                                                 int* __restrict__ cursor,
                                                 const float* __restrict__ b_ih,
                                                 const float* __restrict__ b_hh,
                                                 float* __restrict__ bias_gx) {
  if (blockIdx.x == 3) {
    const int t = threadIdx.x;
    if (t <= MAXD) {
      int ss = 0;
      for (int dd = t + 1; dd <= MAXD; ++dd) ss += hist[dd];
      cursor[t] = ss;
    }
  } else {
    const int gt = blockIdx.x * 256 + threadIdx.x;
    if (gt < 768) bias_gx[gt] = b_ih[gt] + (gt < 512 ? b_hh[gt] : 0.0f);
  }
}

__global__ __launch_bounds__(256) void perm_scatter(const int* __restrict__ cnt,
                                                    int* __restrict__ cursor, int* __restrict__ perm) {
  const int d = blockIdx.x * 256 + threadIdx.x;
  const int rank = atomicAdd(&cursor[cnt[d]], 1);
  perm[rank] = d;
}

// ================= generic bf16 MFMA GEMM =================
template <int ACT, int GS, int OMODE, int VT>
__global__ __launch_bounds__(256) void gemm_bf16(
    const unsigned short* __restrict__ A, const int* __restrict__ gidx,
    const unsigned short* __restrict__ W, const float* __restrict__ bias,
    float* __restrict__ C, unsigned short* __restrict__ Cb,
    unsigned short* __restrict__ Vt, int M, int N, int K) {
  __shared__ unsigned short As[64 * 64];
  __shared__ unsigned short Ws[64 * 64];
  __shared__ int ridx[64];
  const int bm = blockIdx.y * 64, bn = blockIdx.x * 64;
  const int tid = threadIdx.x;
  const int ln = tid & 63, w = tid >> 6;
  const int jc = ln & 15, kq = ln >> 4;
  const int srow = tid >> 2, q = tid & 3;

  if constexpr (GS > 0) {
    if (tid < 64) ridx[tid] = gidx[(size_t)(bm + tid) * GS];
    __syncthreads();
  }
  const size_t arow = (GS > 0) ? (size_t)ridx[srow] : (size_t)(bm + srow);
  const unsigned short* Asrc = A + arow * K + q * 16;
  const unsigned short* Wsrc = W + (size_t)(bn + srow) * K + q * 16;

  f32x4 acc[2][2];
#pragma unroll
  for (int i = 0; i < 2; ++i)
#pragma unroll
    for (int j = 0; j < 2; ++j) acc[i][j] = (f32x4){0.f, 0.f, 0.f, 0.f};
  const int mrow = (w >> 1) * 32, ncol = (w & 1) * 32;
  const int sb0 = (q * 32) ^ ((srow & 7) << 4);
  const int sb1 = (q * 32 + 16) ^ ((srow & 7) << 4);

  for (int k0 = 0; k0 < K; k0 += 64) {
    __syncthreads();
    {
      const short8 a0 = *(const short8*)(Asrc + k0);
      const short8 a1 = *(const short8*)(Asrc + k0 + 8);
      const short8 w0 = *(const short8*)(Wsrc + k0);
      const short8 w1 = *(const short8*)(Wsrc + k0 + 8);
      *(short8*)((char*)As + srow * 128 + sb0) = a0;
      *(short8*)((char*)As + srow * 128 + sb1) = a1;
      *(short8*)((char*)Ws + srow * 128 + sb0) = w0;
      *(short8*)((char*)Ws + srow * 128 + sb1) = w1;
    }
    __syncthreads();
#pragma unroll
    for (int kt = 0; kt < 2; ++kt) {
      const int kb = kt * 64 + kq * 16;
      short8 a[2], bb[2];
#pragma unroll
      for (int i = 0; i < 2; ++i) {
        const int ra = mrow + i * 16 + jc;
        a[i] = *(const short8*)((const char*)As + ra * 128 + (kb ^ ((ra & 7) << 4)));
        const int rb = ncol + i * 16 + jc;
        bb[i] = *(const short8*)((const char*)Ws + rb * 128 + (kb ^ ((rb & 7) << 4)));
      }
#pragma unroll
      for (int mi = 0; mi < 2; ++mi)
#pragma unroll
        for (int ni = 0; ni < 2; ++ni)
          acc[mi][ni] = __builtin_amdgcn_mfma_f32_16x16x32_bf16(a[mi], bb[ni], acc[mi][ni], 0, 0, 0);
    }
  }
#pragma unroll
  for (int mi = 0; mi < 2; ++mi)
#pragma unroll
    for (int ni = 0; ni < 2; ++ni) {
      const int col = bn + ncol + ni * 16 + jc;
      const float bs = bias[col];
      float vals[4];
#pragma unroll
      for (int v = 0; v < 4; ++v) {
        float val = acc[mi][ni][v] + bs;
        if (ACT == 1) val = fmaxf(val, 0.0f);
        vals[v] = val;
      }
#pragma unroll
      for (int v = 0; v < 4; ++v) {
        const int row = bm + mrow + mi * 16 + kq * 4 + v;
        if constexpr (OMODE != 2) C[(size_t)row * N + col] = vals[v];
        if constexpr (OMODE >= 1) Cb[(size_t)row * N + col] = f2bf(vals[v]);
      }
      if constexpr (VT == 1) {
        if (bn >= 512) {
          short4b p;
#pragma unroll
          for (int v = 0; v < 4; ++v) p[v] = (short)f2bf(vals[v]);
          *(short4b*)(Vt + (size_t)(col - 512) * NN + bm + mrow + mi * 16 + kq * 4) = p;
        }
      }
    }
}

// ================= attn-out GEMM with fused KV-split combine =================
// C[M,256] = ( combine(Op,lp)[M,256] ) @ W[256,256]^T + bias; A built on the fly:
// A[row][k] = (sum_z Op[z][row][k]) / (sum_z lp[z, h=k>>6, row]).  Per 64-wide k-step
// the head h is constant, so the normalizer is one scalar per (row, k-step).
__global__ __launch_bounds__(256) void gemm_attn(
    const float* __restrict__ Op, const float* __restrict__ lp,
    const unsigned short* __restrict__ W, const float* __restrict__ bias,
    float* __restrict__ C) {
  __shared__ unsigned short As[64 * 64];
  __shared__ unsigned short Ws[64 * 64];
  const int bm = blockIdx.y * 64, bn = blockIdx.x * 64;
  const int tid = threadIdx.x;
  const int ln = tid & 63, w = tid >> 6;
  const int jc = ln & 15, kq = ln >> 4;
  const int srow = tid >> 2, q = tid & 3;
  const int row = bm + srow;
  const unsigned short* Wsrc = W + (size_t)(bn + srow) * HDM + q * 16;

  f32x4 acc[2][2];
#pragma unroll
  for (int i = 0; i < 2; ++i)
#pragma unroll
    for (int j = 0; j < 2; ++j) acc[i][j] = (f32x4){0.f, 0.f, 0.f, 0.f};
  const int mrow = (w >> 1) * 32, ncol = (w & 1) * 32;
  const int sb0 = (q * 32) ^ ((srow & 7) << 4);
  const int sb1 = (q * 32 + 16) ^ ((srow & 7) << 4);

  for (int k0 = 0; k0 < HDM; k0 += 64) {
    const int h = k0 >> 6;
    float l = 0.f;
#pragma unroll
    for (int z = 0; z < NS; ++z) l += lp[((size_t)z * 4 + h) * NN + row];
    const float inv = 1.0f / l;
    float a[16];
#pragma unroll
    for (int c4 = 0; c4 < 4; ++c4) {
      float4 s = *(const float4*)(Op + ((size_t)0 * NN + row) * HDM + k0 + q * 16 + c4 * 4);
#pragma unroll
      for (int z = 1; z < NS; ++z) {
        const float4 p = *(const float4*)(Op + ((size_t)z * NN + row) * HDM + k0 + q * 16 + c4 * 4);
        s.x += p.x; s.y += p.y; s.z += p.z; s.w += p.w;
      }
      a[c4 * 4 + 0] = s.x * inv; a[c4 * 4 + 1] = s.y * inv;
      a[c4 * 4 + 2] = s.z * inv; a[c4 * 4 + 3] = s.w * inv;
    }
    short8 a0, a1;
#pragma unroll
    for (int j = 0; j < 8; ++j) { a0[j] = (short)f2bf(a[j]); a1[j] = (short)f2bf(a[8 + j]); }
    __syncthreads();
    {
      const short8 w0 = *(const short8*)Wsrc;
      const short8 w1 = *(const short8*)(Wsrc + 8);
      *(short8*)((char*)As + srow * 128 + sb0) = a0;
      *(short8*)((char*)As + srow * 128 + sb1) = a1;
      *(short8*)((char*)Ws + srow * 128 + sb0) = w0;
      *(short8*)((char*)Ws + srow * 128 + sb1) = w1;
    }
    Wsrc += 64;
    __syncthreads();
#pragma unroll
    for (int kt = 0; kt < 2; ++kt) {
      const int kb = kt * 64 + kq * 16;
      short8 a2[2], bb[2];
#pragma unroll
      for (int i = 0; i < 2; ++i) {
        const int ra = mrow + i * 16 + jc;
        a2[i] = *(const short8*)((const char*)As + ra * 128 + (kb ^ ((ra & 7) << 4)));
        const int rb = ncol + i * 16 + jc;
        bb[i] = *(const short8*)((const char*)Ws + rb * 128 + (kb ^ ((rb & 7) << 4)));
      }
#pragma unroll
      for (int mi = 0; mi < 2; ++mi)
#pragma unroll
        for (int ni = 0; ni < 2; ++ni)
          acc[mi][ni] = __builtin_amdgcn_mfma_f32_16x16x32_bf16(a2[mi], bb[ni], acc[mi][ni], 0, 0, 0);
    }
  }
#pragma unroll
  for (int mi = 0; mi < 2; ++mi)
#pragma unroll
    for (int ni = 0; ni < 2; ++ni) {
      const int col = bn + ncol + ni * 16 + jc;
      const float bs = bias[col];
#pragma unroll
      for (int v = 0; v < 4; ++v) {
        const int orow = bm + mrow + mi * 16 + kq * 4 + v;
        C[(size_t)orow * HDM + col] = acc[mi][ni][v] + bs;
      }
    }
}

// ================= per-block GRU (round-15 structure; structural floor ~94us) =================
__global__ __launch_bounds__(512) void gru_reg(
    const int* __restrict__ perm, const int* __restrict__ cnt,
    const int* __restrict__ srcs, const unsigned short* __restrict__ gx,
    const unsigned short* __restrict__ whhb, const float* __restrict__ b_hh,
    float* __restrict__ x, unsigned short* __restrict__ xb) {
  const int tid = threadIdx.x;
  const int w = tid >> 6;           // wave 0..7
  const int ln = tid & 63;
  const int jc = ln & 15, kq = ln >> 4;
  const int grow = tid >> 5, gpart = tid & 31;

  __shared__ unsigned short Ah[GNPB * 256];
  __shared__ unsigned short Gi[4][GNPB * 768];    // 96 KB ring -> 1 block/CU
  __shared__ int srcs_s[GNPB][MAXD];
  __shared__ int node_s[GNPB], cnt_s[GNPB];
  __shared__ int Rb_s;

  if (tid < GNPB) {
    const int node = perm[blockIdx.x * GNPB + tid];
    node_s[tid] = node;
    cnt_s[tid] = cnt[node];
  }
  for (int i = tid; i < GNPB * 256; i += 512) Ah[i] = 0;
  __syncthreads();
  for (int i = tid; i < GNPB * MAXD; i += 512)
    srcs_s[i >> 6][i & 63] = srcs[(size_t)node_s[i >> 6] * MAXD + (i & 63)];
  if (tid == 0) {
    int mx = 0;
    for (int i = 0; i < GNPB; ++i) mx = mx > cnt_s[i] ? mx : cnt_s[i];
    Rb_s = mx;
  }

  short8 W[48];
#pragma unroll
  for (int g = 0; g < 3; ++g)
#pragma unroll
    for (int ct = 0; ct < 2; ++ct) {
      const unsigned short* src =
          whhb + (size_t)(g * 256 + w * 32 + ct * 16 + jc) * 256 + kq * 8;
#pragma unroll
      for (int kt = 0; kt < 8; ++kt)
        W[(g * 2 + ct) * 8 + kt] = *(const short8*)(src + kt * 32);
    }
  float bhN[2];
  bhN[0] = b_hh[512 + w * 32 + jc];
  bhN[1] = b_hh[512 + w * 32 + 16 + jc];

  float h[8];
#pragma unroll
  for (int i = 0; i < 8; ++i) h[i] = 0.f;

  __syncthreads();
  const int Rb = Rb_s;
  const int myc = cnt_s[grow];

  short8 gv0, gv1, gv2;
  {
    const int sn = (0 < myc) ? srcs_s[grow][0] : 0;
    const unsigned short* gs = gx + (size_t)sn * 768 + gpart * 24;
    gv0 = *(const short8*)gs; gv1 = *(const short8*)(gs + 8); gv2 = *(const short8*)(gs + 16);
  }

  for (int r = 0; r < Rb; ++r) {
    unsigned short* const gslot = Gi[r & 3];
    {
      unsigned short* gd = gslot + grow * 768 + gpart * 24;
      *(short8*)gd = gv0;
      *(short8*)(gd + 8) = gv1;
      *(short8*)(gd + 16) = gv2;
    }
    {
      const int rn = r + 1;
      const int sn = (rn < myc) ? srcs_s[grow][rn] : 0;
      const unsigned short* gs = gx + (size_t)sn * 768 + gpart * 24;
      gv0 = *(const short8*)gs; gv1 = *(const short8*)(gs + 8); gv2 = *(const short8*)(gs + 16);
    }
    f32x4 acc[6];
#pragma unroll
    for (int i = 0; i < 6; ++i) acc[i] = (f32x4){0.f, 0.f, 0.f, 0.f};
#pragma unroll
    for (int kt = 0; kt < 8; ++kt) {
      const short8 a = *(const short8*)((const char*)Ah + jc * 512 +
                                        ((kt * 64 + kq * 16) ^ ((jc & 7) << 4)));
#pragma unroll
      for (int t = 0; t < 6; ++t)
        acc[t] = __builtin_amdgcn_mfma_f32_16x16x32_bf16(a, W[t * 8 + kt], acc[t], 0, 0, 0);
    }
    __syncthreads();
#pragma unroll
    for (int ct = 0; ct < 2; ++ct) {
      const int col = w * 32 + ct * 16 + jc;
#pragma unroll
      for (int v = 0; v < 4; ++v) {
        const int nd = kq * 4 + v;
        if (r < cnt_s[nd]) {
          const float giR = bf2f(gslot[nd * 768 + col]);
          const float giZ = bf2f(gslot[nd * 768 + 256 + col]);
          const float giN = bf2f(gslot[nd * 768 + 512 + col]);
          const float rr = sigf(giR + acc[ct][v]);
          const float zz = sigf(giZ + acc[2 + ct][v]);
          const float nn2 = tanh_fast(giN + rr * (acc[4 + ct][v] + bhN[ct]));
          const float hn = (1.0f - zz) * nn2 + zz * h[ct * 4 + v];
          h[ct * 4 + v] = hn;
          *(unsigned short*)((char*)Ah + nd * 512 + ((col * 2) ^ ((nd & 7) << 4))) = f2bf(hn);
        }
      }
    }
    __syncthreads();
  }
#pragma unroll
  for (int ct = 0; ct < 2; ++ct) {
    const int col = w * 32 + ct * 16 + jc;
#pragma unroll
    for (int v = 0; v < 4; ++v) {
      const int gnode = node_s[kq * 4 + v];
      x[(size_t)gnode * HDM + col] = h[ct * 4 + v];
      xb[(size_t)gnode * HDM + col] = f2bf(h[ct * 4 + v]);
    }
  }
}

// ================= bf16 MFMA flash attention, KV-split, fixed-max softmax =================
__global__ __launch_bounds__(256) void flash_part(
    const unsigned short* __restrict__ qkvb, const unsigned short* __restrict__ vtb,
    float* __restrict__ Op, float* __restrict__ lp) {
  const int h = blockIdx.y;
  const int qb = blockIdx.x * 64;
  const int z = blockIdx.z;
  const int tid = threadIdx.x;
  const int ln = tid & 63, w = tid >> 6;
  const int jc = ln & 15, kq = ln >> 4;
  __shared__ unsigned short Ks[2][64 * 64];
  __shared__ unsigned short Vts[2][64 * 64];
  __shared__ unsigned short Ps[4][16 * 64];   // per-wave private

  short8 aq[2];
  {
    const unsigned short* qsrc = qkvb + (size_t)(qb + w * 16 + jc) * 768 + h * 64 + kq * 8;
    aq[0] = *(const short8*)qsrc;
    aq[1] = *(const short8*)(qsrc + 32);
  }
  f32x4 accO[4];
#pragma unroll
  for (int nf = 0; nf < 4; ++nf) accO[nf] = (f32x4){0.f, 0.f, 0.f, 0.f};
  float psum[4] = {0.f, 0.f, 0.f, 0.f};

  const int srow = tid >> 2, sc = tid & 3;
  const int swb0 = (sc * 32) ^ ((srow & 7) << 4);
  const int swb1 = (sc * 32 + 16) ^ ((srow & 7) << 4);
  const int k0 = z * 1024;
  unsigned short* Pw = Ps[w];

  short8 kr0, kr1, vr0, vr1;
  {
    const unsigned short* ksrc = qkvb + (size_t)(k0 + srow) * 768 + 256 + h * 64 + sc * 16;
    kr0 = *(const short8*)ksrc; kr1 = *(const short8*)(ksrc + 8);
    const unsigned short* vsrc = vtb + (size_t)(h * 64 + srow) * 4096 + k0 + sc * 16;
    vr0 = *(const short8*)vsrc; vr1 = *(const short8*)(vsrc + 8);
  }

  for (int t = 0; t < 16; ++t) {
    const int cur = t & 1;
    *(short8*)((char*)Ks[cur] + srow * 128 + swb0) = kr0;
    *(short8*)((char*)Ks[cur] + srow * 128 + swb1) = kr1;
    *(short8*)((char*)Vts[cur] + srow * 128 + swb0) = vr0;
    *(short8*)((char*)Vts[cur] + srow * 128 + swb1) = vr1;
    {
      const int tn = t < 15 ? t + 1 : 15;
      const unsigned short* ksrc =
          qkvb + (size_t)(k0 + tn * 64 + srow) * 768 + 256 + h * 64 + sc * 16;
      kr0 = *(const short8*)ksrc; kr1 = *(const short8*)(ksrc + 8);
      const unsigned short* vsrc =
          vtb + (size_t)(h * 64 + srow) * 4096 + k0 + tn * 64 + sc * 16;
      vr0 = *(const short8*)vsrc; vr1 = *(const short8*)(vsrc + 8);
    }
    __syncthreads();
    // ---- S = Q @ K^T ----
    f32x4 s[4];
#pragma unroll
    for (int kt = 0; kt < 4; ++kt) s[kt] = (f32x4){0.f, 0.f, 0.f, 0.f};
    __builtin_amdgcn_s_setprio(1);
#pragma unroll
    for (int ks = 0; ks < 2; ++ks) {
#pragma unroll
      for (int kt = 0; kt < 4; ++kt) {
        const int brow = kt * 16 + jc;
        const short8 bk = *(const short8*)((const char*)Ks[cur] + brow * 128 +
                                           ((ks * 64 + kq * 16) ^ ((brow & 7) << 4)));
        s[kt] = __builtin_amdgcn_mfma_f32_16x16x32_bf16(aq[ks], bk, s[kt], 0, 0, 0);
      }
    }
    __builtin_amdgcn_s_setprio(0);
    // ---- P = exp(S/8 - 8), local psum accumulate, wave-private store ----
#pragma unroll
    for (int kt = 0; kt < 4; ++kt) {
#pragma unroll
      for (int v = 0; v < 4; ++v) {
        const float pv = __expf(s[kt][v] * 0.125f - 8.0f);
        psum[v] += pv;
        const int pr = kq * 4 + v;
        const int cb = kt * 32 + jc * 2;
        *(unsigned short*)((char*)Pw + pr * 128 + (cb ^ ((pr & 7) << 4))) = f2bf(pv);
      }
    }
    asm volatile("s_waitcnt lgkmcnt(0)" ::: "memory");
    __builtin_amdgcn_sched_barrier(0);
    // ---- O += P @ V ----
    __builtin_amdgcn_s_setprio(1);
#pragma unroll
    for (int ks = 0; ks < 2; ++ks) {
      const short8 ap = *(const short8*)((const char*)Pw + jc * 128 +
                                         ((ks * 64 + kq * 16) ^ ((jc & 7) << 4)));
#pragma unroll
      for (int nf = 0; nf < 4; ++nf) {
        const int brow = nf * 16 + jc;
        const short8 bv = *(const short8*)((const char*)Vts[cur] + brow * 128 +
                                           ((ks * 64 + kq * 16) ^ ((brow & 7) << 4)));
        accO[nf] = __builtin_amdgcn_mfma_f32_16x16x32_bf16(ap, bv, accO[nf], 0, 0, 0);
      }
    }
    __builtin_amdgcn_s_setprio(0);
  }
#pragma unroll
  for (int v = 0; v < 4; ++v) {
    float ps = psum[v];
    ps += __shfl_xor(ps, 1);
    ps += __shfl_xor(ps, 2);
    ps += __shfl_xor(ps, 4);
    ps += __shfl_xor(ps, 8);
    psum[v] = ps;
  }
  float* opb = Op + ((size_t)z * NN + qb + w * 16 + kq * 4) * HDM + h * 64 + jc;
#pragma unroll
  for (int nf = 0; nf < 4; ++nf)
#pragma unroll
    for (int v = 0; v < 4; ++v)
      opb[(size_t)v * HDM + nf * 16] = accO[nf][v];
  if (jc == 0) {
#pragma unroll
    for (int v = 0; v < 4; ++v)
      lp[((size_t)z * 4 + h) * NN + qb + w * 16 + kq * 4 + v] = psum[v];
  }
}

// ================= x = LN(x + a); emits fp32 x and bf16 xb =================
__global__ __launch_bounds__(256) void ln_residual(float* __restrict__ x,
                                                   const float* __restrict__ a,
                                                   const float* __restrict__ g,
                                                   const float* __restrict__ b,
                                                   unsigned short* __restrict__ xb) {
  const int lane = threadIdx.x & 63;
  const int row = blockIdx.x * 4 + (threadIdx.x >> 6);
  float v[4];
  float s = 0.0f;
#pragma unroll
  for (int j = 0; j < 4; j++) {
    const int col = j * 64 + lane;
    v[j] = x[(size_t)row * HDM + col] + a[(size_t)row * HDM + col];
    s += v[j];
  }
#pragma unroll
  for (int off = 32; off > 0; off >>= 1) s += __shfl_xor(s, off);
  const float mu = s * (1.0f / HDM);
  float vs = 0.0f;
#pragma unroll
  for (int j = 0; j < 4; j++) {
    const float d = v[j] - mu;
    vs += d * d;
  }
#pragma unroll
  for (int off = 32; off > 0; off >>= 1) vs += __shfl_xor(vs, off);
  const float rinv = 1.0f / sqrtf(vs * (1.0f / HDM) + 1e-5f);
#pragma unroll
  for (int j = 0; j < 4; j++) {
    const int col = j * 64 + lane;
    const float val = g[col] * (v[j] - mu) * rinv + b[col];
    x[(size_t)row * HDM + col] = val;
    xb[(size_t)row * HDM + col] = f2bf(val);
  }
}

// ================= fused edge predictor: gather-cat + MLP + sigmoid =================
__global__ __launch_bounds__(256) void ep_fused(const float* __restrict__ refined,
                                                const int* __restrict__ cand,
                                                const float* __restrict__ e1w,
                                                const float* __restrict__ e1b,
                                                const float* __restrict__ e2w,
                                                const float* __restrict__ e2b,
                                                float* __restrict__ out) {
  const int c = blockIdx.x;
  const int t = threadIdx.x;
  __shared__ float hrow[512];
  __shared__ float eph_s[256];
  const int n0 = cand[2 * c], n1 = cand[2 * c + 1];
  hrow[t] = refined[(size_t)n0 * HDM + t];
  hrow[256 + t] = refined[(size_t)n1 * HDM + t];
  __syncthreads();
  const float4* wrow = (const float4*)(e1w + (size_t)t * 512);
  float s = 0.f;
#pragma unroll 8
  for (int k = 0; k < 128; ++k) {
    const float4 w4 = wrow[k];
    const float4 h4 = *(const float4*)(hrow + k * 4);
    s += w4.x * h4.x + w4.y * h4.y + w4.z * h4.z + w4.w * h4.w;
  }
  eph_s[t] = fmaxf(s + e1b[t], 0.0f);
  __syncthreads();
  if (t < 64) {
    float p = 0.f;
#pragma unroll
    for (int j = 0; j < 4; ++j) p += eph_s[j * 64 + t] * e2w[j * 64 + t];
#pragma unroll
    for (int off = 32; off > 0; off >>= 1) p += __shfl_xor(p, off);
    if (t == 0) out[c] = 1.0f / (1.0f + __expf(-(p + e2b[0])));
  }
}

extern "C" void kernel_launch(void* const* d_in, const int* in_sizes, int n_in,
                              void* d_out, int out_size, void* d_ws, size_t ws_size,
                              hipStream_t stream) {
  (void)in_sizes; (void)n_in; (void)out_size; (void)ws_size;
  const float* nf    = (const float*)d_in[0];
  const int*   edges = (const int*)d_in[1];
  const int*   cand  = (const int*)d_in[2];
  const float* w_ih  = (const float*)d_in[3];
  const float* w_hh  = (const float*)d_in[4];
  const float* b_ih  = (const float*)d_in[5];
  const float* b_hh  = (const float*)d_in[6];
  const float* ain_w = (const float*)d_in[7];
  const float* ain_b = (const float*)d_in[8];
  const float* aout_w = (const float*)d_in[9];
  const float* aout_b = (const float*)d_in[10];
  const float* ln1g = (const float*)d_in[11];
  const float* ln1b = (const float*)d_in[12];
  const float* f1w  = (const float*)d_in[13];
  const float* f1b  = (const float*)d_in[14];
  const float* f2w  = (const float*)d_in[15];
  const float* f2b  = (const float*)d_in[16];
  const float* ln2g = (const float*)d_in[17];
  const float* ln2b = (const float*)d_in[18];
  const float* s1w  = (const float*)d_in[19];
  const float* s1b  = (const float*)d_in[20];
  const float* s2w  = (const float*)d_in[21];
  const float* s2b  = (const float*)d_in[22];
  const float* e1w  = (const float*)d_in[23];
  const float* e1b  = (const float*)d_in[24];
  const float* e2w  = (const float*)d_in[25];
  const float* e2b  = (const float*)d_in[26];
  float* out = (float*)d_out;

  char* wp = (char*)d_ws;
  float* x        = (float*)wp; wp += (size_t)NN * HDM * 4;            // 4 MB
  unsigned short* xb = (unsigned short*)wp; wp += (size_t)NN * HDM * 2; // 2 MB
  unsigned short* wseg = (unsigned short*)wp; wp += (size_t)CVT_TOT * 2; // 5.05 MB
  int* cnt        = (int*)wp;  wp += (size_t)NN * 4;
  int* lists      = (int*)wp;  wp += (size_t)NN * MAXD * 4;            // 1 MB
  int* srcs       = (int*)wp;  wp += (size_t)NN * MAXD * 4;            // 1 MB
  int* meta       = (int*)wp;  wp += 256 * 4;
  float* bias_gx  = (float*)wp; wp += 1024 * 4;
  int* perm       = (int*)wp;  wp += (size_t)NN * 4;
  unsigned short* gx = (unsigned short*)wp; wp += (size_t)NN * 768 * 2; // 6 MB
  char* uni       = wp;        // transformer buffers
  unsigned short* qkvb   = (unsigned short*)uni;                      // 6 MB
  unsigned short* vtb    = (unsigned short*)(uni + 6291456);          // 2 MB
  float* abuf    = (float*)(uni + 8388608);                           // 4 MB
  unsigned short* abuf_b = (unsigned short*)(uni + 12582912);         // 2 MB
  float* fbuf    = (float*)(uni + 14680064);                          // 16 MB (also attn Op)
  float* Op      = fbuf;
  unsigned short* fbuf_b = (unsigned short*)(uni + 31457280);         // 8 MB (also attn lp)
  float* lp      = (float*)(uni + 31457280);                          // 256 KB
  float* refined = (float*)(uni + 39845888);                          // 4 MB

  unsigned short* nf_b  = wseg;
  unsigned short* wihb  = wseg + 524288;
  unsigned short* ainb  = wseg + 622592;
  unsigned short* aoutb = wseg + 1015808;
  unsigned short* f1b_  = wseg + 1146880;
  unsigned short* f2b_  = wseg + 1671168;
  unsigned short* s1b_  = wseg + 2195456;
  unsigned short* s2b_  = wseg + 2260992;
  unsigned short* whhb  = wseg + 2326528;

  int* hist   = meta;
  int* cursor = meta + 128;

  cvt_weights<<<2464, 256, 0, stream>>>(nf, w_ih, ain_w, aout_w, f1w, f2w, s1w, s2w, w_hh,
                                        wseg, cnt, meta);
  build_pos<<<NE / 256, 256, 0, stream>>>(edges, cnt, lists);
  sort_srcs<<<NN / 256, 256, 0, stream>>>(edges, cnt, lists, srcs, hist);
  scan_prep<<<4, 256, 0, stream>>>(hist, cursor, b_ih, b_hh, bias_gx);
  perm_scatter<<<NN / 256, 256, 0, stream>>>(cnt, cursor, perm);

  // gx[n] = bf16( nf[n] @ w_ih^T + b_ih (+ b_hh R/Z) )   [NN,768], K=128
  gemm_bf16<0, 0, 2, 0><<<dim3(12, NN / 64), 256, 0, stream>>>(
      nf_b, nullptr, wihb, bias_gx, nullptr, gx, nullptr, NN, 768, IND);
  gru_reg<<<NN / GNPB, 512, 0, stream>>>(perm, cnt, srcs, gx, whhb, b_hh, x, xb);

  for (int l = 0; l < NL; l++) {
    gemm_bf16<0, 0, 2, 1><<<dim3(12, 64), 256, 0, stream>>>(
        xb, nullptr, ainb + (size_t)l * 196608, ain_b + l * 768, nullptr, qkvb, vtb, NN, 768, HDM);
    flash_part<<<dim3(64, 4, NS), 256, 0, stream>>>(qkvb, vtb, Op, lp);
    gemm_attn<<<dim3(4, 64), 256, 0, stream>>>(
        Op, lp, aoutb + (size_t)l * 65536, aout_b + l * 256, abuf);
    ln_residual<<<NN / 4, 256, 0, stream>>>(x, abuf, ln1g + l * 256, ln1b + l * 256, xb);
    gemm_bf16<1, 0, 2, 0><<<dim3(16, 64), 256, 0, stream>>>(
        xb, nullptr, f1b_ + (size_t)l * 262144, f1b + l * 1024, nullptr, fbuf_b, nullptr, NN, 1024, HDM);
    gemm_bf16<0, 0, 0, 0><<<dim3(4, 64), 256, 0, stream>>>(
        fbuf_b, nullptr, f2b_ + (size_t)l * 262144, f2b + l * 256, abuf, nullptr, nullptr, NN, 256, 1024);
    ln_residual<<<NN / 4, 256, 0, stream>>>(x, abuf, ln2g + l * 256, ln2b + l * 256, xb);
  }

  gemm_bf16<1, 0, 2, 0><<<dim3(4, 64), 256, 0, stream>>>(
      xb, nullptr, s1b_, s1b, nullptr, abuf_b, nullptr, NN, 256, HDM);
  gemm_bf16<0, 0, 0, 0><<<dim3(4, 64), 256, 0, stream>>>(
      abuf_b, nullptr, s2b_, s2b, refined, nullptr, nullptr, NN, 256, HDM);
  ep_fused<<<NCAND, 256, 0, stream>>>(refined, cand, e1w, e1b, e2w, e2b, out);
}

// Round 17
// 350.163 us; speedup vs baseline: 1.0262x; 1.0262x over previous
//
#include <hip/hip_runtime.h>
#include <math.h>

#define NN     4096
#define NE     32768
#define NCAND  64
#define IND    128
#define HDM    256
#define NL     2
#define MAXD   64
#define GNPB   16   // GRU nodes per block
#define NS     4    // attention KV splits

typedef __attribute__((ext_vector_type(8))) short short8;
typedef __attribute__((ext_vector_type(4))) short short4b;
typedef __attribute__((ext_vector_type(4))) float f32x4;

__device__ __forceinline__ float sigf(float x) { return 1.0f / (1.0f + __expf(-x)); }
__device__ __forceinline__ float tanh_fast(float x) {
  float e = __expf(-2.0f * fabsf(x));
  float r = (1.0f - e) / (1.0f + e);
  return x < 0.0f ? -r : r;
}
__device__ __forceinline__ unsigned short f2bf(float f) {
  unsigned int x = __float_as_uint(f);
  x += 0x7fffu + ((x >> 16) & 1u);   // RNE
  return (unsigned short)(x >> 16);
}
__device__ __forceinline__ float bf2f(unsigned short u) {
  return __uint_as_float(((unsigned int)u) << 16);
}

// ================= weight/feature fp32->bf16 conversion + buffer zeroing =================
#define CVT_TOT 2523136
__global__ __launch_bounds__(256) void cvt_weights(
    const float* __restrict__ nf, const float* __restrict__ wih,
    const float* __restrict__ ain, const float* __restrict__ aout,
    const float* __restrict__ f1, const float* __restrict__ f2,
    const float* __restrict__ s1, const float* __restrict__ s2,
    const float* __restrict__ whh, unsigned short* __restrict__ dst,
    int* __restrict__ cnt, int* __restrict__ meta) {
  if (blockIdx.x < 16) cnt[blockIdx.x * 256 + threadIdx.x] = 0;
  else if (blockIdx.x == 16) meta[threadIdx.x] = 0;
  const size_t e = ((size_t)blockIdx.x * 256 + threadIdx.x) * 4;
  if (e >= CVT_TOT) return;
  const float* src;
  if (e < 524288)       src = nf   + e;
  else if (e < 622592)  src = wih  + (e - 524288);
  else if (e < 1015808) src = ain  + (e - 622592);
  else if (e < 1146880) src = aout + (e - 1015808);
  else if (e < 1671168) src = f1   + (e - 1146880);
  else if (e < 2195456) src = f2   + (e - 1671168);
  else if (e < 2260992) src = s1   + (e - 2195456);
  else if (e < 2326528) src = s2   + (e - 2260992);
  else                  src = whh  + (e - 2326528);
  const float4 v = *(const float4*)src;
  dst[e + 0] = f2bf(v.x); dst[e + 1] = f2bf(v.y);
  dst[e + 2] = f2bf(v.z); dst[e + 3] = f2bf(v.w);
}

// ================= GRU preprocessing =================
__global__ __launch_bounds__(256) void build_pos(const int* __restrict__ edges,
                                                 int* __restrict__ cnt, int* __restrict__ lists) {
  const int e = blockIdx.x * 256 + threadIdx.x;
  const int d = edges[2 * e + 1];
  const int slot = atomicAdd(&cnt[d], 1);
  if (slot < MAXD) lists[(size_t)d * MAXD + slot] = e;
}

__global__ __launch_bounds__(256) void sort_srcs(const int* __restrict__ edges,
                                                 int* __restrict__ cnt,
                                                 const int* __restrict__ lists,
                                                 int* __restrict__ srcs,
                                                 int* __restrict__ hist) {
  __shared__ int Ls[256][65];
  const int t = threadIdx.x;
  const int d = blockIdx.x * 256 + t;
  int c = cnt[d]; if (c > MAXD) c = MAXD;
  for (int i = 0; i < c; ++i) Ls[t][i] = lists[(size_t)d * MAXD + i];
  for (int i = 1; i < c; ++i) {
    const int key = Ls[t][i];
    int j = i - 1;
    while (j >= 0 && Ls[t][j] > key) { Ls[t][j + 1] = Ls[t][j]; --j; }
    Ls[t][j + 1] = key;
  }
  for (int i = 0; i < c; ++i) srcs[(size_t)d * MAXD + i] = edges[2 * Ls[t][i]];
  cnt[d] = c;
  atomicAdd(&hist[c], 1);
}

__global__ __launch_bounds__(256) void scan_prep(const int* __restrict__ hist,
                                                 int* __restrict__ cursor,
                                                 const float* __restrict__ b_ih,
                                                 const float* __restrict__ b_hh,
                                                 float* __restrict__ bias_gx) {
  if (blockIdx.x == 3) {
    const int t = threadIdx.x;
    if (t <= MAXD) {
      int ss = 0;
      for (int dd = t + 1; dd <= MAXD; ++dd) ss += hist[dd];
      cursor[t] = ss;
    }
  } else {
    const int gt = blockIdx.x * 256 + threadIdx.x;
    if (gt < 768) bias_gx[gt] = b_ih[gt] + (gt < 512 ? b_hh[gt] : 0.0f);
  }
}

__global__ __launch_bounds__(256) void perm_scatter(const int* __restrict__ cnt,
                                                    int* __restrict__ cursor, int* __restrict__ perm) {
  const int d = blockIdx.x * 256 + threadIdx.x;
  const int rank = atomicAdd(&cursor[cnt[d]], 1);
  perm[rank] = d;
}

// ================= generic bf16 MFMA GEMM =================
template <int ACT, int GS, int OMODE, int VT>
__global__ __launch_bounds__(256) void gemm_bf16(
    const unsigned short* __restrict__ A, const int* __restrict__ gidx,
    const unsigned short* __restrict__ W, const float* __restrict__ bias,
    float* __restrict__ C, unsigned short* __restrict__ Cb,
    unsigned short* __restrict__ Vt, int M, int N, int K) {
  __shared__ unsigned short As[64 * 64];
  __shared__ unsigned short Ws[64 * 64];
  __shared__ int ridx[64];
  const int bm = blockIdx.y * 64, bn = blockIdx.x * 64;
  const int tid = threadIdx.x;
  const int ln = tid & 63, w = tid >> 6;
  const int jc = ln & 15, kq = ln >> 4;
  const int srow = tid >> 2, q = tid & 3;

  if constexpr (GS > 0) {
    if (tid < 64) ridx[tid] = gidx[(size_t)(bm + tid) * GS];
    __syncthreads();
  }
  const size_t arow = (GS > 0) ? (size_t)ridx[srow] : (size_t)(bm + srow);
  const unsigned short* Asrc = A + arow * K + q * 16;
  const unsigned short* Wsrc = W + (size_t)(bn + srow) * K + q * 16;

  f32x4 acc[2][2];
#pragma unroll
  for (int i = 0; i < 2; ++i)
#pragma unroll
    for (int j = 0; j < 2; ++j) acc[i][j] = (f32x4){0.f, 0.f, 0.f, 0.f};
  const int mrow = (w >> 1) * 32, ncol = (w & 1) * 32;
  const int sb0 = (q * 32) ^ ((srow & 7) << 4);
  const int sb1 = (q * 32 + 16) ^ ((srow & 7) << 4);

  for (int k0 = 0; k0 < K; k0 += 64) {
    __syncthreads();
    {
      const short8 a0 = *(const short8*)(Asrc + k0);
      const short8 a1 = *(const short8*)(Asrc + k0 + 8);
      const short8 w0 = *(const short8*)(Wsrc + k0);
      const short8 w1 = *(const short8*)(Wsrc + k0 + 8);
      *(short8*)((char*)As + srow * 128 + sb0) = a0;
      *(short8*)((char*)As + srow * 128 + sb1) = a1;
      *(short8*)((char*)Ws + srow * 128 + sb0) = w0;
      *(short8*)((char*)Ws + srow * 128 + sb1) = w1;
    }
    __syncthreads();
#pragma unroll
    for (int kt = 0; kt < 2; ++kt) {
      const int kb = kt * 64 + kq * 16;
      short8 a[2], bb[2];
#pragma unroll
      for (int i = 0; i < 2; ++i) {
        const int ra = mrow + i * 16 + jc;
        a[i] = *(const short8*)((const char*)As + ra * 128 + (kb ^ ((ra & 7) << 4)));
        const int rb = ncol + i * 16 + jc;
        bb[i] = *(const short8*)((const char*)Ws + rb * 128 + (kb ^ ((rb & 7) << 4)));
      }
#pragma unroll
      for (int mi = 0; mi < 2; ++mi)
#pragma unroll
        for (int ni = 0; ni < 2; ++ni)
          acc[mi][ni] = __builtin_amdgcn_mfma_f32_16x16x32_bf16(a[mi], bb[ni], acc[mi][ni], 0, 0, 0);
    }
  }
#pragma unroll
  for (int mi = 0; mi < 2; ++mi)
#pragma unroll
    for (int ni = 0; ni < 2; ++ni) {
      const int col = bn + ncol + ni * 16 + jc;
      const float bs = bias[col];
      float vals[4];
#pragma unroll
      for (int v = 0; v < 4; ++v) {
        float val = acc[mi][ni][v] + bs;
        if (ACT == 1) val = fmaxf(val, 0.0f);
        vals[v] = val;
      }
#pragma unroll
      for (int v = 0; v < 4; ++v) {
        const int row = bm + mrow + mi * 16 + kq * 4 + v;
        if constexpr (OMODE != 2) C[(size_t)row * N + col] = vals[v];
        if constexpr (OMODE >= 1) Cb[(size_t)row * N + col] = f2bf(vals[v]);
      }
      if constexpr (VT == 1) {
        if (bn >= 512) {
          short4b p;
#pragma unroll
          for (int v = 0; v < 4; ++v) p[v] = (short)f2bf(vals[v]);
          *(short4b*)(Vt + (size_t)(col - 512) * NN + bm + mrow + mi * 16 + kq * 4) = p;
        }
      }
    }
}

// ================= per-block GRU (structural floor ~94us; rounds 7-15 ledger) =================
__global__ __launch_bounds__(512) void gru_reg(
    const int* __restrict__ perm, const int* __restrict__ cnt,
    const int* __restrict__ srcs, const unsigned short* __restrict__ gx,
    const unsigned short* __restrict__ whhb, const float* __restrict__ b_hh,
    float* __restrict__ x, unsigned short* __restrict__ xb) {
  const int tid = threadIdx.x;
  const int w = tid >> 6;           // wave 0..7
  const int ln = tid & 63;
  const int jc = ln & 15, kq = ln >> 4;
  const int grow = tid >> 5, gpart = tid & 31;

  __shared__ unsigned short Ah[GNPB * 256];       // 8 KB   [node][col] bf16, swz
  __shared__ unsigned short Gi[4][GNPB * 768];    // 96 KB  gx staging ring (slot = r&3)
  __shared__ int srcs_s[GNPB][MAXD];              // 4 KB
  __shared__ int node_s[GNPB], cnt_s[GNPB];
  __shared__ int Rb_s;

  if (tid < GNPB) {
    const int node = perm[blockIdx.x * GNPB + tid];
    node_s[tid] = node;
    cnt_s[tid] = cnt[node];
  }
  for (int i = tid; i < GNPB * 256; i += 512) Ah[i] = 0;
  __syncthreads();
  for (int i = tid; i < GNPB * MAXD; i += 512)
    srcs_s[i >> 6][i & 63] = srcs[(size_t)node_s[i >> 6] * MAXD + (i & 63)];
  if (tid == 0) {
    int mx = 0;
    for (int i = 0; i < GNPB; ++i) mx = mx > cnt_s[i] ? mx : cnt_s[i];
    Rb_s = mx;
  }

  short8 W[48];
#pragma unroll
  for (int g = 0; g < 3; ++g)
#pragma unroll
    for (int ct = 0; ct < 2; ++ct) {
      const unsigned short* src =
          whhb + (size_t)(g * 256 + w * 32 + ct * 16 + jc) * 256 + kq * 8;
#pragma unroll
      for (int kt = 0; kt < 8; ++kt)
        W[(g * 2 + ct) * 8 + kt] = *(const short8*)(src + kt * 32);
    }
  float bhN[2];
  bhN[0] = b_hh[512 + w * 32 + jc];
  bhN[1] = b_hh[512 + w * 32 + 16 + jc];

  float h[8];
#pragma unroll
  for (int i = 0; i < 8; ++i) h[i] = 0.f;

  __syncthreads();
  const int Rb = Rb_s;
  const int myc = cnt_s[grow];

  short8 gv0, gv1, gv2;
  {
    const int sn = (0 < myc) ? srcs_s[grow][0] : 0;
    const unsigned short* gs = gx + (size_t)sn * 768 + gpart * 24;
    gv0 = *(const short8*)gs; gv1 = *(const short8*)(gs + 8); gv2 = *(const short8*)(gs + 16);
  }

  for (int r = 0; r < Rb; ++r) {
    unsigned short* const gslot = Gi[r & 3];
    {
      unsigned short* gd = gslot + grow * 768 + gpart * 24;
      *(short8*)gd = gv0;
      *(short8*)(gd + 8) = gv1;
      *(short8*)(gd + 16) = gv2;
    }
    {
      const int rn = r + 1;
      const int sn = (rn < myc) ? srcs_s[grow][rn] : 0;
      const unsigned short* gs = gx + (size_t)sn * 768 + gpart * 24;
      gv0 = *(const short8*)gs; gv1 = *(const short8*)(gs + 8); gv2 = *(const short8*)(gs + 16);
    }
    f32x4 acc[6];
#pragma unroll
    for (int i = 0; i < 6; ++i) acc[i] = (f32x4){0.f, 0.f, 0.f, 0.f};
#pragma unroll
    for (int kt = 0; kt < 8; ++kt) {
      const short8 a = *(const short8*)((const char*)Ah + jc * 512 +
                                        ((kt * 64 + kq * 16) ^ ((jc & 7) << 4)));
#pragma unroll
      for (int t = 0; t < 6; ++t)
        acc[t] = __builtin_amdgcn_mfma_f32_16x16x32_bf16(a, W[t * 8 + kt], acc[t], 0, 0, 0);
    }
    __syncthreads();
#pragma unroll
    for (int ct = 0; ct < 2; ++ct) {
      const int col = w * 32 + ct * 16 + jc;
#pragma unroll
      for (int v = 0; v < 4; ++v) {
        const int nd = kq * 4 + v;
        if (r < cnt_s[nd]) {
          const float giR = bf2f(gslot[nd * 768 + col]);
          const float giZ = bf2f(gslot[nd * 768 + 256 + col]);
          const float giN = bf2f(gslot[nd * 768 + 512 + col]);
          const float rr = sigf(giR + acc[ct][v]);
          const float zz = sigf(giZ + acc[2 + ct][v]);
          const float nn2 = tanh_fast(giN + rr * (acc[4 + ct][v] + bhN[ct]));
          const float hn = (1.0f - zz) * nn2 + zz * h[ct * 4 + v];
          h[ct * 4 + v] = hn;
          *(unsigned short*)((char*)Ah + nd * 512 + ((col * 2) ^ ((nd & 7) << 4))) = f2bf(hn);
        }
      }
    }
    __syncthreads();
  }
#pragma unroll
  for (int ct = 0; ct < 2; ++ct) {
    const int col = w * 32 + ct * 16 + jc;
#pragma unroll
    for (int v = 0; v < 4; ++v) {
      const int gnode = node_s[kq * 4 + v];
      x[(size_t)gnode * HDM + col] = h[ct * 4 + v];
      xb[(size_t)gnode * HDM + col] = f2bf(h[ct * 4 + v]);
    }
  }
}

// ================= bf16 MFMA flash attention, KV-split, fixed-max softmax =================
__global__ __launch_bounds__(256) void flash_part(
    const unsigned short* __restrict__ qkvb, const unsigned short* __restrict__ vtb,
    float* __restrict__ Op, float* __restrict__ lp) {
  const int h = blockIdx.y;
  const int qb = blockIdx.x * 64;
  const int z = blockIdx.z;
  const int tid = threadIdx.x;
  const int ln = tid & 63, w = tid >> 6;
  const int jc = ln & 15, kq = ln >> 4;
  __shared__ unsigned short Ks[2][64 * 64];
  __shared__ unsigned short Vts[2][64 * 64];
  __shared__ unsigned short Ps[4][16 * 64];   // per-wave private

  short8 aq[2];
  {
    const unsigned short* qsrc = qkvb + (size_t)(qb + w * 16 + jc) * 768 + h * 64 + kq * 8;
    aq[0] = *(const short8*)qsrc;
    aq[1] = *(const short8*)(qsrc + 32);
  }
  f32x4 accO[4];
#pragma unroll
  for (int nf = 0; nf < 4; ++nf) accO[nf] = (f32x4){0.f, 0.f, 0.f, 0.f};
  float psum[4] = {0.f, 0.f, 0.f, 0.f};

  const int srow = tid >> 2, sc = tid & 3;
  const int swb0 = (sc * 32) ^ ((srow & 7) << 4);
  const int swb1 = (sc * 32 + 16) ^ ((srow & 7) << 4);
  const int k0 = z * 1024;
  unsigned short* Pw = Ps[w];

  short8 kr0, kr1, vr0, vr1;
  {
    const unsigned short* ksrc = qkvb + (size_t)(k0 + srow) * 768 + 256 + h * 64 + sc * 16;
    kr0 = *(const short8*)ksrc; kr1 = *(const short8*)(ksrc + 8);
    const unsigned short* vsrc = vtb + (size_t)(h * 64 + srow) * 4096 + k0 + sc * 16;
    vr0 = *(const short8*)vsrc; vr1 = *(const short8*)(vsrc + 8);
  }

  for (int t = 0; t < 16; ++t) {
    const int cur = t & 1;
    *(short8*)((char*)Ks[cur] + srow * 128 + swb0) = kr0;
    *(short8*)((char*)Ks[cur] + srow * 128 + swb1) = kr1;
    *(short8*)((char*)Vts[cur] + srow * 128 + swb0) = vr0;
    *(short8*)((char*)Vts[cur] + srow * 128 + swb1) = vr1;
    {
      const int tn = t < 15 ? t + 1 : 15;
      const unsigned short* ksrc =
          qkvb + (size_t)(k0 + tn * 64 + srow) * 768 + 256 + h * 64 + sc * 16;
      kr0 = *(const short8*)ksrc; kr1 = *(const short8*)(ksrc + 8);
      const unsigned short* vsrc =
          vtb + (size_t)(h * 64 + srow) * 4096 + k0 + tn * 64 + sc * 16;
      vr0 = *(const short8*)vsrc; vr1 = *(const short8*)(vsrc + 8);
    }
    __syncthreads();
    // ---- S = Q @ K^T ----
    f32x4 s[4];
#pragma unroll
    for (int kt = 0; kt < 4; ++kt) s[kt] = (f32x4){0.f, 0.f, 0.f, 0.f};
    __builtin_amdgcn_s_setprio(1);
#pragma unroll
    for (int ks = 0; ks < 2; ++ks) {
#pragma unroll
      for (int kt = 0; kt < 4; ++kt) {
        const int brow = kt * 16 + jc;
        const short8 bk = *(const short8*)((const char*)Ks[cur] + brow * 128 +
                                           ((ks * 64 + kq * 16) ^ ((brow & 7) << 4)));
        s[kt] = __builtin_amdgcn_mfma_f32_16x16x32_bf16(aq[ks], bk, s[kt], 0, 0, 0);
      }
    }
    __builtin_amdgcn_s_setprio(0);
    // ---- P = exp(S/8 - 8), local psum accumulate, wave-private store ----
#pragma unroll
    for (int kt = 0; kt < 4; ++kt) {
#pragma unroll
      for (int v = 0; v < 4; ++v) {
        const float pv = __expf(s[kt][v] * 0.125f - 8.0f);
        psum[v] += pv;
        const int pr = kq * 4 + v;
        const int cb = kt * 32 + jc * 2;
        *(unsigned short*)((char*)Pw + pr * 128 + (cb ^ ((pr & 7) << 4))) = f2bf(pv);
      }
    }
    asm volatile("s_waitcnt lgkmcnt(0)" ::: "memory");
    __builtin_amdgcn_sched_barrier(0);
    // ---- O += P @ V ----
    __builtin_amdgcn_s_setprio(1);
#pragma unroll
    for (int ks = 0; ks < 2; ++ks) {
      const short8 ap = *(const short8*)((const char*)Pw + jc * 128 +
                                         ((ks * 64 + kq * 16) ^ ((jc & 7) << 4)));
#pragma unroll
      for (int nf = 0; nf < 4; ++nf) {
        const int brow = nf * 16 + jc;
        const short8 bv = *(const short8*)((const char*)Vts[cur] + brow * 128 +
                                           ((ks * 64 + kq * 16) ^ ((brow & 7) << 4)));
        accO[nf] = __builtin_amdgcn_mfma_f32_16x16x32_bf16(ap, bv, accO[nf], 0, 0, 0);
      }
    }
    __builtin_amdgcn_s_setprio(0);
  }
#pragma unroll
  for (int v = 0; v < 4; ++v) {
    float ps = psum[v];
    ps += __shfl_xor(ps, 1);
    ps += __shfl_xor(ps, 2);
    ps += __shfl_xor(ps, 4);
    ps += __shfl_xor(ps, 8);
    psum[v] = ps;
  }
  float* opb = Op + ((size_t)z * NN + qb + w * 16 + kq * 4) * HDM + h * 64 + jc;
#pragma unroll
  for (int nf = 0; nf < 4; ++nf)
#pragma unroll
    for (int v = 0; v < 4; ++v)
      opb[(size_t)v * HDM + nf * 16] = accO[nf][v];
  if (jc == 0) {
#pragma unroll
    for (int v = 0; v < 4; ++v)
      lp[((size_t)z * 4 + h) * NN + qb + w * 16 + kq * 4 + v] = psum[v];
  }
}

// combine: out = (sum_z Op) / (sum_z l)  -> bf16
__global__ __launch_bounds__(256) void attn_combine(const float* __restrict__ Op,
                                                    const float* __restrict__ lp,
                                                    unsigned short* __restrict__ outb) {
  const int row = blockIdx.x * 4 + (threadIdx.x >> 6);
  const int lane = threadIdx.x & 63;
  const int col = lane * 4;
  const int h = col >> 6;
  float l = 0.f;
  float4 o = {0.f, 0.f, 0.f, 0.f};
#pragma unroll
  for (int z = 0; z < NS; ++z) {
    l += lp[((size_t)z * 4 + h) * NN + row];
    const float4 p = *(const float4*)(Op + ((size_t)z * NN + row) * HDM + col);
    o.x += p.x; o.y += p.y; o.z += p.z; o.w += p.w;
  }
  const float inv = 1.0f / l;
  unsigned short* d = outb + (size_t)row * HDM + col;
  d[0] = f2bf(o.x * inv); d[1] = f2bf(o.y * inv);
  d[2] = f2bf(o.z * inv); d[3] = f2bf(o.w * inv);
}

// ================= x = LN(x + a); emits fp32 x and bf16 xb =================
__global__ __launch_bounds__(256) void ln_residual(float* __restrict__ x,
                                                   const float* __restrict__ a,
                                                   const float* __restrict__ g,
                                                   const float* __restrict__ b,
                                                   unsigned short* __restrict__ xb) {
  const int lane = threadIdx.x & 63;
  const int row = blockIdx.x * 4 + (threadIdx.x >> 6);
  float v[4];
  float s = 0.0f;
#pragma unroll
  for (int j = 0; j < 4; j++) {
    const int col = j * 64 + lane;
    v[j] = x[(size_t)row * HDM + col] + a[(size_t)row * HDM + col];
    s += v[j];
  }
#pragma unroll
  for (int off = 32; off > 0; off >>= 1) s += __shfl_xor(s, off);
  const float mu = s * (1.0f / HDM);
  float vs = 0.0f;
#pragma unroll
  for (int j = 0; j < 4; j++) {
    const float d = v[j] - mu;
    vs += d * d;
  }
#pragma unroll
  for (int off = 32; off > 0; off >>= 1) vs += __shfl_xor(vs, off);
  const float rinv = 1.0f / sqrtf(vs * (1.0f / HDM) + 1e-5f);
#pragma unroll
  for (int j = 0; j < 4; j++) {
    const int col = j * 64 + lane;
    const float val = g[col] * (v[j] - mu) * rinv + b[col];
    x[(size_t)row * HDM + col] = val;
    xb[(size_t)row * HDM + col] = f2bf(val);
  }
}

// ================= fused edge predictor: gather-cat + MLP + sigmoid =================
__global__ __launch_bounds__(256) void ep_fused(const float* __restrict__ refined,
                                                const int* __restrict__ cand,
                                                const float* __restrict__ e1w,
                                                const float* __restrict__ e1b,
                                                const float* __restrict__ e2w,
                                                const float* __restrict__ e2b,
                                                float* __restrict__ out) {
  const int c = blockIdx.x;
  const int t = threadIdx.x;
  __shared__ float hrow[512];
  __shared__ float eph_s[256];
  const int n0 = cand[2 * c], n1 = cand[2 * c + 1];
  hrow[t] = refined[(size_t)n0 * HDM + t];
  hrow[256 + t] = refined[(size_t)n1 * HDM + t];
  __syncthreads();
  const float4* wrow = (const float4*)(e1w + (size_t)t * 512);
  float s = 0.f;
#pragma unroll 8
  for (int k = 0; k < 128; ++k) {
    const float4 w4 = wrow[k];
    const float4 h4 = *(const float4*)(hrow + k * 4);
    s += w4.x * h4.x + w4.y * h4.y + w4.z * h4.z + w4.w * h4.w;
  }
  eph_s[t] = fmaxf(s + e1b[t], 0.0f);
  __syncthreads();
  if (t < 64) {
    float p = 0.f;
#pragma unroll
    for (int j = 0; j < 4; ++j) p += eph_s[j * 64 + t] * e2w[j * 64 + t];
#pragma unroll
    for (int off = 32; off > 0; off >>= 1) p += __shfl_xor(p, off);
    if (t == 0) out[c] = 1.0f / (1.0f + __expf(-(p + e2b[0])));
  }
}

extern "C" void kernel_launch(void* const* d_in, const int* in_sizes, int n_in,
                              void* d_out, int out_size, void* d_ws, size_t ws_size,
                              hipStream_t stream) {
  (void)in_sizes; (void)n_in; (void)out_size; (void)ws_size;
  const float* nf    = (const float*)d_in[0];
  const int*   edges = (const int*)d_in[1];
  const int*   cand  = (const int*)d_in[2];
  const float* w_ih  = (const float*)d_in[3];
  const float* w_hh  = (const float*)d_in[4];
  const float* b_ih  = (const float*)d_in[5];
  const float* b_hh  = (const float*)d_in[6];
  const float* ain_w = (const float*)d_in[7];
  const float* ain_b = (const float*)d_in[8];
  const float* aout_w = (const float*)d_in[9];
  const float* aout_b = (const float*)d_in[10];
  const float* ln1g = (const float*)d_in[11];
  const float* ln1b = (const float*)d_in[12];
  const float* f1w  = (const float*)d_in[13];
  const float* f1b  = (const float*)d_in[14];
  const float* f2w  = (const float*)d_in[15];
  const float* f2b  = (const float*)d_in[16];
  const float* ln2g = (const float*)d_in[17];
  const float* ln2b = (const float*)d_in[18];
  const float* s1w  = (const float*)d_in[19];
  const float* s1b  = (const float*)d_in[20];
  const float* s2w  = (const float*)d_in[21];
  const float* s2b  = (const float*)d_in[22];
  const float* e1w  = (const float*)d_in[23];
  const float* e1b  = (const float*)d_in[24];
  const float* e2w  = (const float*)d_in[25];
  const float* e2b  = (const float*)d_in[26];
  float* out = (float*)d_out;

  char* wp = (char*)d_ws;
  float* x        = (float*)wp; wp += (size_t)NN * HDM * 4;            // 4 MB
  unsigned short* xb = (unsigned short*)wp; wp += (size_t)NN * HDM * 2; // 2 MB
  unsigned short* wseg = (unsigned short*)wp; wp += (size_t)CVT_TOT * 2; // 5.05 MB
  int* cnt        = (int*)wp;  wp += (size_t)NN * 4;
  int* lists      = (int*)wp;  wp += (size_t)NN * MAXD * 4;            // 1 MB
  int* srcs       = (int*)wp;  wp += (size_t)NN * MAXD * 4;            // 1 MB
  int* meta       = (int*)wp;  wp += 256 * 4;
  float* bias_gx  = (float*)wp; wp += 1024 * 4;
  int* perm       = (int*)wp;  wp += (size_t)NN * 4;
  unsigned short* gx = (unsigned short*)wp; wp += (size_t)NN * 768 * 2; // 6 MB
  char* uni       = wp;        // transformer buffers
  unsigned short* qkvb   = (unsigned short*)uni;                      // 6 MB
  unsigned short* vtb    = (unsigned short*)(uni + 6291456);          // 2 MB
  float* abuf    = (float*)(uni + 8388608);                           // 4 MB
  unsigned short* abuf_b = (unsigned short*)(uni + 12582912);         // 2 MB
  float* fbuf    = (float*)(uni + 14680064);                          // 16 MB (also attn Op)
  float* Op      = fbuf;
  unsigned short* fbuf_b = (unsigned short*)(uni + 31457280);         // 8 MB (also attn lp)
  float* lp      = (float*)(uni + 31457280);                          // 256 KB
  float* refined = (float*)(uni + 39845888);                          // 4 MB

  unsigned short* nf_b  = wseg;
  unsigned short* wihb  = wseg + 524288;
  unsigned short* ainb  = wseg + 622592;
  unsigned short* aoutb = wseg + 1015808;
  unsigned short* f1b_  = wseg + 1146880;
  unsigned short* f2b_  = wseg + 1671168;
  unsigned short* s1b_  = wseg + 2195456;
  unsigned short* s2b_  = wseg + 2260992;
  unsigned short* whhb  = wseg + 2326528;

  int* hist   = meta;
  int* cursor = meta + 128;

  cvt_weights<<<2464, 256, 0, stream>>>(nf, w_ih, ain_w, aout_w, f1w, f2w, s1w, s2w, w_hh,
                                        wseg, cnt, meta);
  build_pos<<<NE / 256, 256, 0, stream>>>(edges, cnt, lists);
  sort_srcs<<<NN / 256, 256, 0, stream>>>(edges, cnt, lists, srcs, hist);
  scan_prep<<<4, 256, 0, stream>>>(hist, cursor, b_ih, b_hh, bias_gx);
  perm_scatter<<<NN / 256, 256, 0, stream>>>(cnt, cursor, perm);

  // gx[n] = bf16( nf[n] @ w_ih^T + b_ih (+ b_hh R/Z) )   [NN,768], K=128
  gemm_bf16<0, 0, 2, 0><<<dim3(12, NN / 64), 256, 0, stream>>>(
      nf_b, nullptr, wihb, bias_gx, nullptr, gx, nullptr, NN, 768, IND);
  gru_reg<<<NN / GNPB, 512, 0, stream>>>(perm, cnt, srcs, gx, whhb, b_hh, x, xb);

  for (int l = 0; l < NL; l++) {
    gemm_bf16<0, 0, 2, 1><<<dim3(12, 64), 256, 0, stream>>>(
        xb, nullptr, ainb + (size_t)l * 196608, ain_b + l * 768, nullptr, qkvb, vtb, NN, 768, HDM);
    flash_part<<<dim3(64, 4, NS), 256, 0, stream>>>(qkvb, vtb, Op, lp);
    attn_combine<<<NN / 4, 256, 0, stream>>>(Op, lp, abuf_b);
    gemm_bf16<0, 0, 0, 0><<<dim3(4, 64), 256, 0, stream>>>(
        abuf_b, nullptr, aoutb + (size_t)l * 65536, aout_b + l * 256, fbuf, nullptr, nullptr, NN, 256, HDM);
    ln_residual<<<NN / 4, 256, 0, stream>>>(x, fbuf, ln1g + l * 256, ln1b + l * 256, xb);
    gemm_bf16<1, 0, 2, 0><<<dim3(16, 64), 256, 0, stream>>>(
        xb, nullptr, f1b_ + (size_t)l * 262144, f1b + l * 1024, nullptr, fbuf_b, nullptr, NN, 1024, HDM);
    gemm_bf16<0, 0, 0, 0><<<dim3(4, 64), 256, 0, stream>>>(
        fbuf_b, nullptr, f2b_ + (size_t)l * 262144, f2b + l * 256, abuf, nullptr, nullptr, NN, 256, 1024);
    ln_residual<<<NN / 4, 256, 0, stream>>>(x, abuf, ln2g + l * 256, ln2b + l * 256, xb);
  }

  gemm_bf16<1, 0, 2, 0><<<dim3(4, 64), 256, 0, stream>>>(
      xb, nullptr, s1b_, s1b, nullptr, abuf_b, nullptr, NN, 256, HDM);
  gemm_bf16<0, 0, 0, 0><<<dim3(4, 64), 256, 0, stream>>>(
      abuf_b, nullptr, s2b_, s2b, refined, nullptr, nullptr, NN, 256, HDM);
  ep_fused<<<NCAND, 256, 0, stream>>>(refined, cand, e1w, e1b, e2w, e2b, out);
}